// Round 6
// baseline (208.949 us; speedup 1.0000x reference)
//
#include <hip/hip_runtime.h>

#define EPS 1e-7f
#define LOG2E 1.44269504088896340736f

constexpr int SEGS  = 64;   // i-split: 32x64 = 2048 blocks = 8 blocks/CU (full occupancy)
constexpr int BLOCK = 256;
// d_ws is re-poisoned to 0xAA bytes before every timed launch -> tickets start here.
constexpr unsigned POISON = 0xAAAAAAAAu;

// Fused kernel, thread-per-output-j (scalar-broadcast loads — R5 showed the
// wave-per-j variant pushes 805 MB through L1/L2 and runs 5.7x slower).
// Phase 1: each (bx, seg) block accumulates its i-segment into partial[seg][j].
// Phase 2: last block of each column-group (via global ticket) reduces the 64
// partials and normalizes — saves the second dispatch.
__global__ __launch_bounds__(BLOCK) void nw_fused(
    const float2* __restrict__ x,        // M x 2 query points
    const float2* __restrict__ inputs,   // N x 2 data points
    const float*  __restrict__ outputs,  // N
    const float*  __restrict__ bw,       // M
    float2*       __restrict__ partial,  // SEGS x M  (num, den)
    unsigned*     __restrict__ tickets,  // gridDim.x counters (poisoned 0xAA..)
    float*        __restrict__ out,      // M
    int N, int M)
{
    const int bx  = blockIdx.x;
    const int j   = bx * BLOCK + threadIdx.x;
    const int seg = blockIdx.y;
    const int per = (N + SEGS - 1) / SEGS;
    const int i0  = seg * per;
    const int i1  = min(N, i0 + per);

    float r = 0.f, rx0 = 0.f, ry0 = 0.f;
    if (j < M) {
        float2 xj = x[j];
        float  b  = bw[j];
        r   = sqrtf(LOG2E / (2.0f * b * b));
        rx0 = r * xj.x;
        ry0 = r * xj.y;
    }

    // w = exp2(-((r*px - rx0)^2 + (r*py - ry0)^2)); neg folds into v_exp_f32.
    // i is block-uniform -> inputs/outputs scalarize to batched s_loads.
    float num0 = 0.f, num1 = 0.f, den0 = 0.f, den1 = 0.f;
    int i = i0;
    #pragma unroll 8
    for (; i + 1 < i1; i += 2) {
        float2 pa = inputs[i];
        float2 pb = inputs[i + 1];
        float  oa = outputs[i];
        float  ob = outputs[i + 1];
        float dxa = fmaf(r, pa.x, -rx0);
        float dya = fmaf(r, pa.y, -ry0);
        float dxb = fmaf(r, pb.x, -rx0);
        float dyb = fmaf(r, pb.y, -ry0);
        float ta  = fmaf(dxa, dxa, dya * dya);
        float tb  = fmaf(dxb, dxb, dyb * dyb);
        float wa  = __builtin_amdgcn_exp2f(-ta);
        float wb  = __builtin_amdgcn_exp2f(-tb);
        num0 = fmaf(wa, oa, num0);
        num1 = fmaf(wb, ob, num1);
        den0 += wa;
        den1 += wb;
    }
    if (i < i1) {
        float2 pa = inputs[i];
        float  oa = outputs[i];
        float dxa = fmaf(r, pa.x, -rx0);
        float dya = fmaf(r, pa.y, -ry0);
        float ta  = fmaf(dxa, dxa, dya * dya);
        float wa  = __builtin_amdgcn_exp2f(-ta);
        num0 = fmaf(wa, oa, num0);
        den0 += wa;
    }

    if (j < M) partial[(size_t)seg * M + j] = make_float2(num0 + num1, den0 + den1);

    // --- last-block finalize (ticket pattern, device scope) ---
    __shared__ bool isLast;
    __threadfence();                       // release: partial visible device-wide
    if (threadIdx.x == 0) {
        unsigned old = atomicAdd(&tickets[bx], 1u);   // device-scope by default
        isLast = (old == POISON + (unsigned)(SEGS - 1)) ||
                 (old == (unsigned)(SEGS - 1));       // hedge: zeroed-ws case
    }
    __syncthreads();
    if (isLast) {
        __threadfence();                   // acquire: see all 64 partials
        float num = 0.f, den = 0.f;
        #pragma unroll
        for (int s = 0; s < SEGS; ++s) {
            float2 p = partial[(size_t)s * M + j];   // coalesced across j
            num += p.x;
            den += p.y;
        }
        if (j < M) out[j] = num / (den + EPS);
    }
}

extern "C" void kernel_launch(void* const* d_in, const int* in_sizes, int n_in,
                              void* d_out, int out_size, void* d_ws, size_t ws_size,
                              hipStream_t stream) {
    // setup_inputs() dict order: x (M*2), inputs (N*2), outputs (N), bandwidth (M)
    const float2* x       = (const float2*)d_in[0];
    const float2* inputs  = (const float2*)d_in[1];
    const float*  outputs = (const float*) d_in[2];
    const float*  bwv     = (const float*) d_in[3];
    const int N = in_sizes[2];   // outputs element count
    const int M = in_sizes[3];   // bandwidth element count
    float*        out     = (float*)d_out;

    // ws layout: [0, SEGS*M*8) partials ; then per-column-group tickets
    float2*   partial = (float2*)d_ws;
    unsigned* tickets = (unsigned*)((char*)d_ws + (size_t)SEGS * M * sizeof(float2));

    dim3 grid((M + BLOCK - 1) / BLOCK, SEGS);   // 32 x 64
    nw_fused<<<grid, BLOCK, 0, stream>>>(x, inputs, outputs, bwv,
                                         partial, tickets, out, N, M);
}

// Round 7
// 75.955 us; speedup vs baseline: 2.7510x; 2.7510x over previous
//
#include <hip/hip_runtime.h>

#define EPS 1e-7f
#define LOG2E 1.44269504088896340736f

constexpr int BLOCK = 1024;        // 16 waves/block
constexpr int JB    = 32;          // outputs (j) per block
constexpr int SS    = BLOCK / JB;  // 32 i-segments per block
constexpr int CHUNK = 1024;        // points staged per LDS chunk (16 KB)

// Single dispatch. Block b owns j in [b*JB, b*JB+JB). Thread = (jj, ss):
// lane-fast jj so each wave holds all 32 jj's x 2 ss's -> LDS reads are
// 2-distinct-address broadcasts (free, m136). Data points staged per chunk
// into LDS as (px, py, s=px^2+py^2, o); inner loop is
//   t = c0*s + c1*px + c2*py + c3 ;  w = exp2(t)   [k<0 folded into c0..c3]
// = 3 fma + exp + fma + add = 5 VALU + 1 trans + 1 ds_read_b128 per point.
// Cross-segment reduction is block-local LDS (no 2nd dispatch, no fences,
// no d_ws partials -- R3/R6 showed grid-scope sync costs 95-150 us here).
__global__ __launch_bounds__(BLOCK, 4) void nw_block(
    const float2* __restrict__ x,        // M x 2 query points
    const float2* __restrict__ inputs,   // N x 2 data points
    const float*  __restrict__ outputs,  // N
    const float*  __restrict__ bw,       // M
    float*        __restrict__ out,      // M
    int N, int M)
{
    __shared__ float4 pts[CHUNK];        // (px, py, s, o)
    __shared__ float2 red[SS][JB];       // per-(segment, jj) partials

    const int tid = threadIdx.x;
    const int jj  = tid & (JB - 1);
    const int ss  = tid / JB;
    const int j   = blockIdx.x * JB + jj;

    float c0 = 0.f, c1 = 0.f, c2 = 0.f, c3 = 0.f;
    if (j < M) {
        float2 xj = x[j];
        float  b  = bw[j];
        float  k  = -LOG2E / (2.0f * b * b);     // < 0
        c0 = k;
        c1 = -2.0f * k * xj.x;
        c2 = -2.0f * k * xj.y;
        c3 = k * fmaf(xj.x, xj.x, xj.y * xj.y);
    }

    float num = 0.f, den = 0.f;
    for (int base = 0; base < N; base += CHUNK) {
        const int cnt = min(CHUNK, N - base);
        // stage one chunk: 1024 threads, one point each (coalesced dwordx2+dword)
        if (tid < cnt) {
            float2 p = inputs[base + tid];
            float  o = outputs[base + tid];
            pts[tid] = make_float4(p.x, p.y, fmaf(p.x, p.x, p.y * p.y), o);
        } else if (tid < CHUNK) {
            pts[tid] = make_float4(0.f, 0.f, 3.0e38f, 0.f);  // pad: c0*s -> -inf -> w = 0
        }
        __syncthreads();

        // each thread: its contiguous CHUNK/SS = 32 points of this chunk
        const float4* my = &pts[ss * (CHUNK / SS)];
        #pragma unroll 8
        for (int l = 0; l < CHUNK / SS; ++l) {
            float4 p = my[l];                        // ds_read_b128, 2-addr broadcast
            float  t = fmaf(c0, p.z, fmaf(c1, p.x, fmaf(c2, p.y, c3)));
            float  w = __builtin_amdgcn_exp2f(t);
            num = fmaf(w, p.w, num);
            den += w;
        }
        __syncthreads();
    }

    // block-local cross-segment reduction
    red[ss][jj] = make_float2(num, den);
    __syncthreads();
    if (tid < JB) {                                  // ss == 0, jj == tid
        float n = 0.f, d = 0.f;
        #pragma unroll
        for (int s = 0; s < SS; ++s) {
            n += red[s][tid].x;
            d += red[s][tid].y;
        }
        const int jo = blockIdx.x * JB + tid;
        if (jo < M) out[jo] = n / (d + EPS);
    }
}

extern "C" void kernel_launch(void* const* d_in, const int* in_sizes, int n_in,
                              void* d_out, int out_size, void* d_ws, size_t ws_size,
                              hipStream_t stream) {
    // setup_inputs() dict order: x (M*2), inputs (N*2), outputs (N), bandwidth (M)
    const float2* x       = (const float2*)d_in[0];
    const float2* inputs  = (const float2*)d_in[1];
    const float*  outputs = (const float*) d_in[2];
    const float*  bwv     = (const float*) d_in[3];
    const int N = in_sizes[2];   // outputs element count
    const int M = in_sizes[3];   // bandwidth element count
    float*        out     = (float*)d_out;

    dim3 grid((M + JB - 1) / JB);    // 256 blocks @ M=8192 -> 1 block/CU, 16 waves
    nw_block<<<grid, BLOCK, 0, stream>>>(x, inputs, outputs, bwv, out, N, M);
}